// Round 1
// baseline (84.330 us; speedup 1.0000x reference)
//
#include <hip/hip_runtime.h>
#include <hip/hip_bf16.h>

#define NB 16384
#define NFEAT 32

__device__ __forceinline__ float cre(float x){
    float c = fminf(fmaxf(x, 0.0f), 127.0f/128.0f);
    return c + 0.1f*(x-c);
}

__global__ void nnue_fused(
    const int* __restrict__ indices,
    const int* __restrict__ offsets,
    const int* __restrict__ which_model,
    const float* __restrict__ embed,
    const float* __restrict__ main_bias,
    const float* __restrict__ vW1, const float* __restrict__ vb1,
    const float* __restrict__ vW2, const float* __restrict__ vb2,
    const float* __restrict__ vW3, const float* __restrict__ vb3,
    const float* __restrict__ pfW, const float* __restrict__ pfb,
    const float* __restrict__ ptW, const float* __restrict__ ptb,
    float* __restrict__ out0, float* __restrict__ out1, float* __restrict__ out2)
{
    __shared__ float lds_emb[4][256];
    __shared__ float lds_h1[4][16];
    __shared__ float lds_h2[4][32];

    const int tid = threadIdx.x;
    const int wv = tid >> 6;
    const int l  = tid & 63;
    const int b  = (blockIdx.x << 2) + wv;

    const int e    = __builtin_amdgcn_readfirstlane(which_model[b]);
    const int base = __builtin_amdgcn_readfirstlane(offsets[b]);
    const int g    = e >> 3;

    // ---- phase 1: gather-accumulate (memory-bound core) ----
    float4 acc = *reinterpret_cast<const float4*>(main_bias + l*4);
    #pragma unroll
    for (int k=0;k<NFEAT;k++){
        const int row = indices[base + k];                    // uniform -> s_load
        const float4 v = *reinterpret_cast<const float4*>(embed + (size_t)row*256 + l*4);
        acc.x += v.x; acc.y += v.y; acc.z += v.z; acc.w += v.w;
    }
    const float psqt = __shfl(acc.x, 0);                      // pre-activation accum[0]
    float4 embv;
    embv.x = cre(acc.x); embv.y = cre(acc.y); embv.z = cre(acc.z); embv.w = cre(acc.w);
    *reinterpret_cast<float4*>(&lds_emb[wv][l*4]) = embv;
    __syncthreads();

    // ---- h1 = cre(vW1[e] @ emb + vb1[e]) : 16 outputs, K=256 ----
    // coalesced flat read: lane l takes W[o=k][h=4l..4l+4) against register emb
    float a1[16];
    {
        const float* w1 = vW1 + e*4096;
        #pragma unroll
        for (int k=0;k<16;k++){
            const float4 w = *reinterpret_cast<const float4*>(w1 + k*256 + l*4);
            a1[k] = w.x*embv.x + w.y*embv.y + w.z*embv.z + w.w*embv.w;
        }
    }
    // merge-butterfly: 16 values reduced over 64 lanes -> lane l holds h1[l&15]
    #pragma unroll
    for (int i=0;i<8;i++){
        float give = (l&1) ? a1[2*i] : a1[2*i+1];
        float keep = (l&1) ? a1[2*i+1] : a1[2*i];
        a1[i] = keep + __shfl_xor(give, 1);
    }
    #pragma unroll
    for (int i=0;i<4;i++){
        float give = ((l>>1)&1) ? a1[2*i] : a1[2*i+1];
        float keep = ((l>>1)&1) ? a1[2*i+1] : a1[2*i];
        a1[i] = keep + __shfl_xor(give, 2);
    }
    #pragma unroll
    for (int i=0;i<2;i++){
        float give = ((l>>2)&1) ? a1[2*i] : a1[2*i+1];
        float keep = ((l>>2)&1) ? a1[2*i+1] : a1[2*i];
        a1[i] = keep + __shfl_xor(give, 4);
    }
    {
        float give = ((l>>3)&1) ? a1[0] : a1[1];
        float keep = ((l>>3)&1) ? a1[1] : a1[0];
        a1[0] = keep + __shfl_xor(give, 8);
    }
    a1[0] += __shfl_xor(a1[0], 16);
    a1[0] += __shfl_xor(a1[0], 32);
    const float h1v = cre(a1[0] + vb1[e*16 + (l&15)]);
    if (l < 16) lds_h1[wv][l] = h1v;
    __syncthreads();

    // ---- h2 = cre(vW2[e] @ h1 + vb2[e]) : 32 outputs, K=16 ----
    const float4 xh1 = *reinterpret_cast<const float4*>(&lds_h1[wv][(l&3)*4]);
    float a2[2];
    #pragma unroll
    for (int k=0;k<2;k++){
        const float4 w = *reinterpret_cast<const float4*>(vW2 + e*512 + k*256 + l*4);
        a2[k] = w.x*xh1.x + w.y*xh1.y + w.z*xh1.z + w.w*xh1.w;
    }
    float v2;
    {
        float give = (l&1) ? a2[0] : a2[1];
        float keep = (l&1) ? a2[1] : a2[0];
        v2 = keep + __shfl_xor(give, 1);
        v2 += __shfl_xor(v2, 2);
    }
    const int o2 = ((l&1)<<4) + (l>>2);
    const float h2v = cre(v2 + vb2[e*32 + o2]);
    if ((l&2)==0) lds_h2[wv][o2] = h2v;
    __syncthreads();

    // ---- value = vW3[e] @ h2 + vb3[e] ; out0 = tanh(value + psqt) ----
    float pv = vW3[e*32 + (l&31)] * lds_h2[wv][l&31];
    pv += __shfl_xor(pv, 1); pv += __shfl_xor(pv, 2); pv += __shfl_xor(pv, 4);
    pv += __shfl_xor(pv, 8); pv += __shfl_xor(pv, 16);
    if (l == 0) out0[b] = tanhf(pv + vb3[e] + psqt);

    // ---- policy heads: 64 outputs each, K=16, input = emb slice by group ----
    const float4 xpf = *reinterpret_cast<const float4*>(&lds_emb[wv][16 + 16*g + (l&3)*4]);
    const float4 xpt = *reinterpret_cast<const float4*>(&lds_emb[wv][80 + 16*g + (l&3)*4]);
    float apf[4], apt[4];
    #pragma unroll
    for (int k=0;k<4;k++){
        const float4 wf = *reinterpret_cast<const float4*>(pfW + e*1024 + k*256 + l*4);
        apf[k] = wf.x*xpf.x + wf.y*xpf.y + wf.z*xpf.z + wf.w*xpf.w;
        const float4 wt = *reinterpret_cast<const float4*>(ptW + e*1024 + k*256 + l*4);
        apt[k] = wt.x*xpt.x + wt.y*xpt.y + wt.z*xpt.z + wt.w*xpt.w;
    }
    #pragma unroll
    for (int i=0;i<2;i++){
        float give = (l&1) ? apf[2*i] : apf[2*i+1];
        float keep = (l&1) ? apf[2*i+1] : apf[2*i];
        apf[i] = keep + __shfl_xor(give, 1);
        give = (l&1) ? apt[2*i] : apt[2*i+1];
        keep = (l&1) ? apt[2*i+1] : apt[2*i];
        apt[i] = keep + __shfl_xor(give, 1);
    }
    float pfv, ptv;
    {
        float give = ((l>>1)&1) ? apf[0] : apf[1];
        float keep = ((l>>1)&1) ? apf[1] : apf[0];
        pfv = keep + __shfl_xor(give, 2);
        give = ((l>>1)&1) ? apt[0] : apt[1];
        keep = ((l>>1)&1) ? apt[1] : apt[0];
        ptv = keep + __shfl_xor(give, 2);
    }
    const int o = ((l&3)<<4) + (l>>2);
    out1[b*64 + o] = pfv + pfb[e*64 + o];
    out2[b*64 + o] = ptv + ptb[e*64 + o];
}

extern "C" void kernel_launch(void* const* d_in, const int* in_sizes, int n_in,
                              void* d_out, int out_size, void* d_ws, size_t ws_size,
                              hipStream_t stream) {
    const int*   indices = (const int*)d_in[0];
    const int*   offsets = (const int*)d_in[1];
    const int*   which   = (const int*)d_in[2];
    const float* embed   = (const float*)d_in[4];
    const float* mbias   = (const float*)d_in[5];
    const float* vW1 = (const float*)d_in[6];
    const float* vb1 = (const float*)d_in[7];
    const float* vW2 = (const float*)d_in[8];
    const float* vb2 = (const float*)d_in[9];
    const float* vW3 = (const float*)d_in[10];
    const float* vb3 = (const float*)d_in[11];
    const float* pfW = (const float*)d_in[12];
    const float* pfb = (const float*)d_in[13];
    const float* ptW = (const float*)d_in[14];
    const float* ptb = (const float*)d_in[15];
    float* out0 = (float*)d_out;
    float* out1 = out0 + NB;
    float* out2 = out1 + (size_t)NB*64;
    nnue_fused<<<NB/4, 256, 0, stream>>>(indices, offsets, which, embed, mbias,
        vW1, vb1, vW2, vb2, vW3, vb3, pfW, pfb, ptW, ptb, out0, out1, out2);
}